// Round 20
// baseline (2159.432 us; speedup 1.0000x reference)
//
#include <hip/hip_runtime.h>
#include <hip/hip_bf16.h>
#include <math.h>

// ---------------- constants ----------------
#define CUTOFF 6.0f
#define NRAD 128
#define NSPH 7
#define DA 256
#define DE 512
#define DT 64
#define DCB 16
#define INV_SQRT2 0.7071067811865476f
#define RBF_GAMMA 227.55555555555554f

typedef __hip_bfloat16 bf16;
typedef __bf16 bf16v;
typedef bf16v bf16x8 __attribute__((ext_vector_type(8)));
typedef float f32x4 __attribute__((ext_vector_type(4)));

static inline int cdiv(int a, int b) { return (a + b - 1) / b; }

__device__ __forceinline__ float silu_f(float v) {
    return v / (1.0f + __expf(-v));
}

__device__ __forceinline__ float to_f(float v) { return v; }
__device__ __forceinline__ float to_f(bf16 v) { return __bfloat162float(v); }

template<typename T> __device__ __forceinline__ T from_f(float v);
template<> __device__ __forceinline__ float from_f<float>(float v) { return v; }
template<> __device__ __forceinline__ bf16 from_f<bf16>(float v) { return __float2bfloat16(v); }

#if defined(__has_builtin)
#if __has_builtin(__builtin_amdgcn_global_load_lds)
#define HAS_GLD 1
#endif
#endif

#ifdef HAS_GLD
// async 16B global->LDS: per-lane global addr, wave-uniform LDS base + lane*16
__device__ __forceinline__ void gld16(const bf16* g, bf16* l) {
    __builtin_amdgcn_global_load_lds(
        (const __attribute__((address_space(1))) void*)g,
        (__attribute__((address_space(3))) void*)l, 16, 0, 0);
}
#endif

// ========== PERSISTENT MFMA bf16 GEMM, 128x128 tile, BK=32, 512 thr (8 waves) =====
// C[M,N] = epi( A @ Bt^T );  Bt PRE-TRANSPOSED [N][K] (ldb = row stride).
// Each block owns a CONTIGUOUS chunk of M-tiles; the 3-deep counted-vmcnt LDS
// pipeline runs continuously across tiles (fill paid once per block). Epilogue
// fires at each tile's last K-step, then acc re-zeroed. Grid = (cdiv(N,128),
// min(768/gx, ntiles)); XCD-bijective swizzle keeps a chunk's col-blocks on one XCD.
template<typename TC, typename TD, bool PRE_ADD, bool HAS_BIAS,
         bool ACT, bool POST_ADD, bool POST_MUL>
__global__ __launch_bounds__(512, 6)
void gemm_pers(const bf16* __restrict__ A, const bf16* __restrict__ Bt,
               TC* __restrict__ C, const TC* __restrict__ Cin,
               const TD* __restrict__ Dop, const float* __restrict__ bias,
               int M, int N, int K, int lda, int ldb, float scale)
{
    __shared__ bf16 lds[3 * 8192];   // 3 bufs x (A 4096 + B 4096 elems), 48 KB
    const int tid = threadIdx.x;

    const int gx = gridDim.x, gy = gridDim.y;
    const int nwg = gx * gy;
    const int bid = blockIdx.y * gx + blockIdx.x;
    const int q = nwg >> 3, r = nwg & 7;
    const int xcd = bid & 7, jj = bid >> 3;
    const int wg = (xcd < r) ? (xcd * (q + 1) + jj) : (r + xcd * q + jj);
    const int x = wg % gx;
    const int g = wg / gx;
    const int bn = x * 128;

    const int KC = K >> 5;
    const int ntiles = (M + 127) >> 7;
    const int tq = ntiles / gy, tr = ntiles % gy;
    const int mt0 = (g < tr) ? g * (tq + 1) : tr * (tq + 1) + (g - tr) * tq;
    const int npg = (g < tr) ? (tq + 1) : tq;
    if (npg <= 0) return;
    const int NS = npg * KC;

    const int w   = tid >> 6;        // 0..7
    const int l   = tid & 63;
    const int l16 = l & 15;
    const int lr4 = (l >> 4) * 4;
    const int wr  = (w >> 2) * 64;
    const int wc  = (w & 3) * 32;
    const int koff = (((l >> 4) ^ ((l16 >> 1) & 3)) << 3);

    f32x4 acc[4][2];
#pragma unroll
    for (int i = 0; i < 4; ++i)
#pragma unroll
        for (int j = 0; j < 2; ++j) acc[i][j] = (f32x4){0.f, 0.f, 0.f, 0.f};

    // staging map: wave w covers tile-rows [w*16, w*16+16) for BOTH A and B.
    const int csw = (((l & 3) ^ ((l >> 3) & 3)) << 3);
    const int rA = w * 16 + (l >> 2);

    int bc = bn + rA; if (bc >= N) bc = N - 1;
    const bf16* pB = Bt + (long)bc * ldb + csw;

    const int wofs = (w * 16) * 32;

    auto STAGE = [&](int smt, int skc, int bo) {
        int ar = (smt << 7) + rA; if (ar >= M) ar = M - 1;
        const bf16* a0 = A + (long)ar * lda + (skc << 5) + csw;
#ifdef HAS_GLD
        gld16(a0, lds + bo + wofs);
        gld16(pB + (skc << 5), lds + bo + 4096 + wofs);
#else
        *(uint4*)(lds + bo + (tid >> 2) * 32 + (tid & 3) * 8) = *(const uint4*)a0;
        *(uint4*)(lds + bo + 4096 + (tid >> 2) * 32 + (tid & 3) * 8) =
            *(const uint4*)(pB + (skc << 5));
#endif
    };

    auto COMPUTE = [&](int bo) {
        const bf16* As_ = lds + bo;
        const bf16* Bs_ = lds + bo + 4096;
        bf16x8 bfr[2];
#pragma unroll
        for (int fn = 0; fn < 2; ++fn)
            bfr[fn] = *(const bf16x8*)&Bs_[(wc + fn * 16 + l16) * 32 + koff];
#pragma unroll
        for (int fm = 0; fm < 4; ++fm) {
            bf16x8 af = *(const bf16x8*)&As_[(wr + fm * 16 + l16) * 32 + koff];
            acc[fm][0] = __builtin_amdgcn_mfma_f32_16x16x32_bf16(af, bfr[0], acc[fm][0], 0, 0, 0);
            acc[fm][1] = __builtin_amdgcn_mfma_f32_16x16x32_bf16(af, bfr[1], acc[fm][1], 0, 0, 0);
        }
    };

    auto EPILOGUE = [&](int cmt) {
        const int bm = cmt << 7;
#pragma unroll
        for (int fm = 0; fm < 4; ++fm) {
#pragma unroll
            for (int fn = 0; fn < 2; ++fn) {
                const int col = bn + wc + fn * 16 + l16;
                if (col < N) {
#pragma unroll
                    for (int r4 = 0; r4 < 4; ++r4) {
                        const int row = bm + wr + fm * 16 + lr4 + r4;
                        if (row < M) {
                            float v = acc[fm][fn][r4];
                            if (PRE_ADD)  v += to_f(Cin[(long)row * N + col]);
                            if (HAS_BIAS) v += bias[col];
                            if (ACT)      v = silu_f(v);
                            if (POST_ADD) v += to_f(Dop[(long)row * N + col]);
                            if (POST_MUL) v *= to_f(Dop[(long)row * N + col]);
                            C[(long)row * N + col] = from_f<TC>(v * scale);
                        }
                    }
                }
                acc[fm][fn] = (f32x4){0.f, 0.f, 0.f, 0.f};
            }
        }
    };

    int smt = mt0, skc = 0;
    auto ADV_S = [&]() { if (++skc == KC) { skc = 0; ++smt; } };

#ifdef HAS_GLD
    if (NS > 0) { STAGE(smt, skc, 0);    ADV_S(); }
    if (NS > 1) { STAGE(smt, skc, 8192); ADV_S(); }
    int cmt = mt0, ckc = 0;
    int boC = 0, boS = 16384;
    for (int s = 0; s < NS; ++s) {
        if (s + 2 < NS) { STAGE(smt, skc, boS); ADV_S(); }
        const int rem = NS - 1 - s;
        __builtin_amdgcn_sched_barrier(0);
        if (rem >= 2)      asm volatile("s_waitcnt vmcnt(4)" ::: "memory");
        else if (rem == 1) asm volatile("s_waitcnt vmcnt(2)" ::: "memory");
        else               asm volatile("s_waitcnt vmcnt(0)" ::: "memory");
        __builtin_amdgcn_sched_barrier(0);
        __builtin_amdgcn_s_barrier();
        __builtin_amdgcn_sched_barrier(0);
        COMPUTE(boC);
        __builtin_amdgcn_s_barrier();
        if (ckc == KC - 1) EPILOGUE(cmt);
        if (++ckc == KC) { ckc = 0; ++cmt; }
        boC += 8192; if (boC > 16384) boC = 0;
        boS += 8192; if (boS > 16384) boS = 0;
    }
#else
    int cmt = mt0, ckc = 0;
    for (int s = 0; s < NS; ++s) {
        STAGE(cmt, ckc, 0);
        __syncthreads();
        COMPUTE(0);
        __syncthreads();
        if (ckc == KC - 1) EPILOGUE(cmt);
        if (++ckc == KC) { ckc = 0; ++cmt; }
    }
#endif
}

// host-side grid chooser for gemm_pers
static inline dim3 pers_grid(int M, int N) {
    int gx = cdiv(N, 128);
    int ntiles = cdiv(M, 128);
    int gy = 768 / gx;
    if (gy > ntiles) gy = ntiles;
    return dim3(gx, gy);
}

// ================= MFMA bf16 GEMM (non-persistent, GMODE=3 fused only) ============
// Round-19 3-deep pipelined kernel, dual-gather + tail.
template<typename TC, typename TD, int GMODE, bool PRE_ADD, bool HAS_BIAS,
         bool ACT, bool POST_ADD, bool POST_MUL>
__global__ __launch_bounds__(512, 6)
void gemm_mfma(const bf16* __restrict__ A, const bf16* __restrict__ A3,
               const bf16* __restrict__ Bt,
               TC* __restrict__ C, const TC* __restrict__ Cin,
               const TD* __restrict__ Dop, const float* __restrict__ bias,
               const int* __restrict__ idx1, const int* __restrict__ idx2,
               int M, int N, int K, int lda, int ldb, float scale)
{
    __shared__ bf16 lds[3 * 8192];
    const int tid = threadIdx.x;

    const int nwg = gridDim.x * gridDim.y;
    const int bid = blockIdx.y * gridDim.x + blockIdx.x;
    const int q = nwg >> 3, r = nwg & 7;
    const int xcd = bid & 7, jj = bid >> 3;
    const int wg = (xcd < r) ? (xcd * (q + 1) + jj) : (r + xcd * q + jj);
    const int bn = (wg % gridDim.x) * 128;
    const int bm = (wg / gridDim.x) * 128;

    const int w   = tid >> 6;
    const int l   = tid & 63;
    const int l16 = l & 15;
    const int lr4 = (l >> 4) * 4;
    const int wr  = (w >> 2) * 64;
    const int wc  = (w & 3) * 32;
    const int koff = (((l >> 4) ^ ((l16 >> 1) & 3)) << 3);

    f32x4 acc[4][2];
#pragma unroll
    for (int i = 0; i < 4; ++i)
#pragma unroll
        for (int j = 0; j < 2; ++j) acc[i][j] = (f32x4){0.f, 0.f, 0.f, 0.f};

    const int csw = (((l & 3) ^ ((l >> 3) & 3)) << 3);
    const int rA = w * 16 + (l >> 2);

    int ar = bm + rA; if (ar >= M) ar = M - 1;
    const bf16* pAa = A + (long)((GMODE >= 2) ? idx1[ar] : ar) * lda + csw;
    const bf16* pAb = (GMODE >= 2) ? (A + (long)idx2[ar] * lda + csw) : pAa;
    const bf16* pAc = (GMODE == 3) ? (A3 + (long)ar * NRAD + csw) : pAa;

    int bc = bn + rA; if (bc >= N) bc = N - 1;
    const bf16* pB = Bt + (long)bc * ldb + csw;

    const int wofs = (w * 16) * 32;

    auto STAGE = [&](int k0, int bo) {
        const bf16* a0;
        if (GMODE == 0) {
            a0 = pAa + k0;
        } else if (GMODE == 2) {
            a0 = (k0 >= DA) ? (pAb + (k0 - DA)) : (pAa + k0);
        } else {
            if (k0 >= 2 * DA)  a0 = pAc + (k0 - 2 * DA);
            else if (k0 >= DA) a0 = pAb + (k0 - DA);
            else               a0 = pAa + k0;
        }
#ifdef HAS_GLD
        gld16(a0, lds + bo + wofs);
        gld16(pB + k0, lds + bo + 4096 + wofs);
#else
        *(uint4*)(lds + bo + (tid >> 2) * 32 + (tid & 3) * 8) = *(const uint4*)a0;
        *(uint4*)(lds + bo + 4096 + (tid >> 2) * 32 + (tid & 3) * 8) = *(const uint4*)(pB + k0);
#endif
    };

    auto COMPUTE = [&](int bo) {
        const bf16* As_ = lds + bo;
        const bf16* Bs_ = lds + bo + 4096;
        bf16x8 bfr[2];
#pragma unroll
        for (int fn = 0; fn < 2; ++fn)
            bfr[fn] = *(const bf16x8*)&Bs_[(wc + fn * 16 + l16) * 32 + koff];
#pragma unroll
        for (int fm = 0; fm < 4; ++fm) {
            bf16x8 af = *(const bf16x8*)&As_[(wr + fm * 16 + l16) * 32 + koff];
            acc[fm][0] = __builtin_amdgcn_mfma_f32_16x16x32_bf16(af, bfr[0], acc[fm][0], 0, 0, 0);
            acc[fm][1] = __builtin_amdgcn_mfma_f32_16x16x32_bf16(af, bfr[1], acc[fm][1], 0, 0, 0);
        }
    };

    const int nt = K >> 5;

#ifdef HAS_GLD
    if (nt > 0) STAGE(0, 0);
    if (nt > 1) STAGE(32, 8192);
    int boC = 0;
    int boS = 16384;
    for (int t = 0; t < nt; ++t) {
        if (t + 2 < nt) STAGE((t + 2) << 5, boS);
        const int rem = nt - 1 - t;
        __builtin_amdgcn_sched_barrier(0);
        if (rem >= 2)      asm volatile("s_waitcnt vmcnt(4)" ::: "memory");
        else if (rem == 1) asm volatile("s_waitcnt vmcnt(2)" ::: "memory");
        else               asm volatile("s_waitcnt vmcnt(0)" ::: "memory");
        __builtin_amdgcn_sched_barrier(0);
        __builtin_amdgcn_s_barrier();
        __builtin_amdgcn_sched_barrier(0);
        COMPUTE(boC);
        __builtin_amdgcn_s_barrier();
        boC += 8192; if (boC > 16384) boC = 0;
        boS += 8192; if (boS > 16384) boS = 0;
    }
#else
    for (int t = 0; t < nt; ++t) {
        STAGE(t << 5, 0);
        __syncthreads();
        COMPUTE(0);
        __syncthreads();
    }
#endif

#pragma unroll
    for (int fm = 0; fm < 4; ++fm) {
#pragma unroll
        for (int fn = 0; fn < 2; ++fn) {
            const int col = bn + wc + fn * 16 + l16;
            if (col < N) {
#pragma unroll
                for (int r4 = 0; r4 < 4; ++r4) {
                    const int row = bm + wr + fm * 16 + lr4 + r4;
                    if (row < M) {
                        float v = acc[fm][fn][r4];
                        if (PRE_ADD)  v += to_f(Cin[(long)row * N + col]);
                        if (HAS_BIAS) v += bias[col];
                        if (ACT)      v = silu_f(v);
                        if (POST_ADD) v += to_f(Dop[(long)row * N + col]);
                        if (POST_MUL) v *= to_f(Dop[(long)row * N + col]);
                        C[(long)row * N + col] = from_f<TC>(v * scale);
                    }
                }
            }
        }
    }
}

// ---------------- f32 -> bf16 convert ----------------
__global__ void f2b_kernel(const float* __restrict__ in, bf16* __restrict__ out, long n)
{
    long i = ((long)blockIdx.x * 256 + threadIdx.x) * 4;
    const long stride = (long)gridDim.x * 256 * 4;
    for (; i < n; i += stride) {
        float4 v = *(const float4*)(in + i);
        bf16 o[4] = {__float2bfloat16(v.x), __float2bfloat16(v.y),
                     __float2bfloat16(v.z), __float2bfloat16(v.w)};
        *(ushort4*)(out + i) = *(const ushort4*)o;
    }
}

// ---------------- f32 [B][K][Nc] -> bf16 transposed [B][Nc][K] (LDS 32x32 tiles) -----
__global__ __launch_bounds__(256)
void t2bT_kernel(const float* __restrict__ in, bf16* __restrict__ out, int K, int Nc)
{
    __shared__ float tile[32][33];
    const long bofs = (long)blockIdx.z * K * Nc;
    const int k0 = blockIdx.y * 32;
    const int n0 = blockIdx.x * 32;
    const int tx = threadIdx.x & 31;
    const int ty = threadIdx.x >> 5;   // 0..7
#pragma unroll
    for (int i = 0; i < 4; ++i) {
        int k = k0 + ty + 8 * i;
        tile[ty + 8 * i][tx] = (k < K && n0 + tx < Nc) ? in[bofs + (long)k * Nc + n0 + tx] : 0.f;
    }
    __syncthreads();
#pragma unroll
    for (int i = 0; i < 4; ++i) {
        int n = n0 + ty + 8 * i;
        if (n < Nc && k0 + tx < K)
            out[bofs + (long)n * K + k0 + tx] = from_f<bf16>(tile[tx][ty + 8 * i]);
    }
}

// ---------------- radial basis ----------------
__global__ __launch_bounds__(128)
void basis_kernel(const float* __restrict__ dist,
                  const float* __restrict__ W_rbf3,
                  bf16* __restrict__ rbf, bf16* __restrict__ rbf3, int E)
{
    __shared__ float s_rbf[NRAD];
    const int e = blockIdx.x;
    if (e >= E) return;
    const int k = threadIdx.x;
    const float d = dist[e];
    const float u = d * (1.0f / CUTOFF);
    float u2 = u * u, u4 = u2 * u2, u5 = u4 * u, u6 = u5 * u, u7 = u6 * u;
    float env = 1.0f - 21.0f * u5 + 35.0f * u6 - 15.0f * u7;
    if (u >= 1.0f) env = 0.0f;
    const float mu = CUTOFF * (float)k / (float)(NRAD - 1);
    const float t = d - mu;
    const float v = env * __expf(-RBF_GAMMA * t * t);
    s_rbf[k] = v;
    rbf[(long)e * NRAD + k] = __float2bfloat16(v);
    __syncthreads();

    if (k < DCB) {
        float acc = 0.f;
        for (int kk = 0; kk < NRAD; ++kk) acc += s_rbf[kk] * W_rbf3[kk * DCB + k];
        rbf3[(long)e * DCB + k] = __float2bfloat16(acc);
    }
}

// ---------------- h init ----------------
__global__ void h_init_kernel(const int* __restrict__ an,
                              const float* __restrict__ table,
                              float* __restrict__ h, int N)
{
    int i = blockIdx.x * 256 + threadIdx.x;
    if (i < N * DA) {
        int a = i >> 8;
        int c = i & 255;
        h[i] = table[(long)an[a] * DA + c];
    }
}

// ================= CSR build =================
__global__ void zeroi_kernel(int* __restrict__ p, int n)
{
    int i = blockIdx.x * 256 + threadIdx.x;
    if (i < n) p[i] = 0;
}
__global__ void copyi_kernel(const int* __restrict__ a, int* __restrict__ b, int n)
{
    int i = blockIdx.x * 256 + threadIdx.x;
    if (i < n) b[i] = a[i];
}
__global__ void count_kernel(const int* __restrict__ idx, int* __restrict__ cnt, int n)
{
    int i = blockIdx.x * 256 + threadIdx.x;
    if (i < n) atomicAdd(&cnt[idx[i]], 1);
}
__global__ __launch_bounds__(256)
void seg_p1(const int* __restrict__ cnt, int* __restrict__ bsum, int n)
{
    __shared__ int s[256];
    int i = blockIdx.x * 256 + threadIdx.x;
    s[threadIdx.x] = (i < n) ? cnt[i] : 0;
    __syncthreads();
    for (int o = 128; o > 0; o >>= 1) {
        if (threadIdx.x < o) s[threadIdx.x] += s[threadIdx.x + o];
        __syncthreads();
    }
    if (threadIdx.x == 0) bsum[blockIdx.x] = s[0];
}
__global__ __launch_bounds__(1024)
void seg_p2(int* __restrict__ bsum, int* __restrict__ off, int nb, int n)
{
    __shared__ int s[1024];
    int v = (threadIdx.x < nb) ? bsum[threadIdx.x] : 0;
    s[threadIdx.x] = v;
    __syncthreads();
    for (int o = 1; o < 1024; o <<= 1) {
        int t = (threadIdx.x >= o) ? s[threadIdx.x - o] : 0;
        __syncthreads();
        s[threadIdx.x] += t;
        __syncthreads();
    }
    if (threadIdx.x < nb) bsum[threadIdx.x] = s[threadIdx.x] - v;  // exclusive
    if (threadIdx.x == nb - 1) off[n] = s[threadIdx.x];            // total
}
__global__ __launch_bounds__(256)
void seg_p3(const int* __restrict__ cnt, const int* __restrict__ bsum,
            int* __restrict__ off, int n)
{
    __shared__ int s[256];
    int i = blockIdx.x * 256 + threadIdx.x;
    int v = (i < n) ? cnt[i] : 0;
    s[threadIdx.x] = v;
    __syncthreads();
    for (int o = 1; o < 256; o <<= 1) {
        int t = (threadIdx.x >= o) ? s[threadIdx.x - o] : 0;
        __syncthreads();
        s[threadIdx.x] += t;
        __syncthreads();
    }
    if (i < n) off[i] = bsum[blockIdx.x] + s[threadIdx.x] - v;
}
__global__ void fill_kernel(const int* __restrict__ idx, int* __restrict__ cur,
                            int* __restrict__ list, int n)
{
    int i = blockIdx.x * 256 + threadIdx.x;
    if (i < n) {
        int p = atomicAdd(&cur[idx[i]], 1);
        list[p] = i;
    }
}

// ---------------- emb16[T,16] = (cheb(cos)@W_sph) * rbf3[ba] ----------------
__global__ __launch_bounds__(256)
void emb16_kernel(const float* __restrict__ cosang,
                  const int* __restrict__ id3_ba,
                  const bf16* __restrict__ rbf3,
                  const float* __restrict__ W_sph,
                  bf16* __restrict__ emb, int T)
{
    __shared__ float s_W[NSPH * DCB];
    const int tid = threadIdx.x;
    if (tid < NSPH * DCB) s_W[tid] = W_sph[tid];
    __syncthreads();
    const long idx = (long)blockIdx.x * 256 + tid;
    if (idx >= (long)T * DCB) return;
    const int t = (int)(idx >> 4);
    const int cc = (int)(idx & 15);
    float c = cosang[t];
    c = fminf(1.0f, fmaxf(-1.0f, c));
    float s0 = 1.0f, s1 = c;
    float a = s_W[0 * DCB + cc] + c * s_W[1 * DCB + cc];
#pragma unroll
    for (int s = 2; s < NSPH; ++s) {
        float s2 = 2.0f * c * s1 - s0;
        a += s2 * s_W[s * DCB + cc];
        s0 = s1; s1 = s2;
    }
    emb[idx] = __float2bfloat16(a * to_f(rbf3[(long)id3_ba[t] * DCB + cc]));
}

// ---------------- x3[e] = sum_{t in bucket(e)} (emb16[t] @ W_up) * xba[ba[t]] ----------------
__global__ __launch_bounds__(256)
void x3_gather_kernel(const int* __restrict__ ca_off, const int* __restrict__ ca_list,
                      const int* __restrict__ id3_ba,
                      const bf16* __restrict__ emb, const bf16* __restrict__ xba,
                      const float* __restrict__ W_up,
                      bf16* __restrict__ x3, int E)
{
    __shared__ float s_Wup[DCB * DT];
    const int tid = threadIdx.x;
    for (int i = tid; i < DCB * DT; i += 256) s_Wup[i] = W_up[i];
    __syncthreads();
    const int e = blockIdx.x * 4 + (tid >> 6);
    const int d = tid & 63;
    if (e >= E) return;
    const int j0 = ca_off[e], j1 = ca_off[e + 1];
    float acc = 0.f;
    for (int j = j0; j < j1; ++j) {
        const int t = ca_list[j];
        const int ba = id3_ba[t];
        const ushort* ep = (const ushort*)(emb + (long)t * DCB);
        float dotv = 0.f;
#pragma unroll
        for (int cc = 0; cc < DCB; ++cc)
            dotv += __uint_as_float((unsigned)ep[cc] << 16) * s_Wup[cc * DT + d];
        acc += dotv * to_f(xba[(long)ba * DT + d]);
    }
    x3[(long)e * DT + d] = from_f<bf16>(acc);
}

// ---------------- s[a] = sum_{e in bucket(a)} g[e]  (g bf16 [E,DE]) ----------------
__global__ __launch_bounds__(256)
void atom_segsum_kernel(const int* __restrict__ tgt_off, const int* __restrict__ tgt_list,
                        const bf16* __restrict__ g, bf16* __restrict__ s_out, int N)
{
    const int a = blockIdx.x;
    if (a >= N) return;
    const int c = threadIdx.x;
    float acc0 = 0.f, acc1 = 0.f;
    const int j0 = tgt_off[a], j1 = tgt_off[a + 1];
    for (int j = j0; j < j1; ++j) {
        const bf16* row = g + (long)tgt_list[j] * DE;
        acc0 += to_f(row[c]);
        acc1 += to_f(row[c + 256]);
    }
    s_out[(long)a * DE + c]       = from_f<bf16>(acc0);
    s_out[(long)a * DE + c + 256] = from_f<bf16>(acc1);
}

// ---------------- final reduce ----------------
__global__ __launch_bounds__(256)
void reduce1_kernel(const float* __restrict__ h, const float* __restrict__ Wout,
                    float* __restrict__ partials, int N)
{
    __shared__ float s[256];
    const int a0 = blockIdx.x * 32;
    const int col = threadIdx.x;
    float acc = 0.f;
    for (int a = 0; a < 32; ++a) {
        int row = a0 + a;
        if (row < N) acc += h[(long)row * DA + col];
    }
    acc *= Wout[col];
    s[col] = acc;
    __syncthreads();
    for (int off = 128; off > 0; off >>= 1) {
        if (col < off) s[col] += s[col + off];
        __syncthreads();
    }
    if (col == 0) partials[blockIdx.x] = s[0];
}

__global__ __launch_bounds__(256)
void reduce2_kernel(const float* __restrict__ partials, float* __restrict__ out, int nb)
{
    __shared__ float s[256];
    float acc = 0.f;
    for (int i = threadIdx.x; i < nb; i += 256) acc += partials[i];
    s[threadIdx.x] = acc;
    __syncthreads();
    for (int off = 128; off > 0; off >>= 1) {
        if (threadIdx.x < off) s[threadIdx.x] += s[threadIdx.x + off];
        __syncthreads();
    }
    if (threadIdx.x == 0) out[0] = s[0];
}

__global__ void diag_kernel(float* out, float v) { out[0] = v; }

// ---------------- launch ----------------
extern "C" void kernel_launch(void* const* d_in, const int* in_sizes, int n_in,
                              void* d_out, int out_size, void* d_ws, size_t ws_size,
                              hipStream_t stream)
{
    const int*   atomic_numbers = (const int*)d_in[0];
    const int*   edge_index     = (const int*)d_in[1];
    const float* distances      = (const float*)d_in[2];
    const int*   id3_ba         = (const int*)d_in[3];
    const int*   id3_ca         = (const int*)d_in[4];
    const float* cos_angles     = (const float*)d_in[5];
    const float* atom_table     = (const float*)d_in[6];
    const float* W_edge         = (const float*)d_in[7];
    const float* b_edge         = (const float*)d_in[8];
    const float* W_rbf3         = (const float*)d_in[9];
    const float* W_sph          = (const float*)d_in[10];
    const float* W_cbf_up       = (const float*)d_in[11];
    const float* W_rbf_h        = (const float*)d_in[12];
    const float* W_ba           = (const float*)d_in[13];
    const float* b_ba           = (const float*)d_in[14];
    const float* W_down         = (const float*)d_in[15];
    const float* W_trip_up      = (const float*)d_in[16];
    const float* W_res_m        = (const float*)d_in[17];
    const float* b_res_m        = (const float*)d_in[18];
    const float* W_e2a          = (const float*)d_in[19];
    const float* W_res_h        = (const float*)d_in[20];
    const float* b_res_h        = (const float*)d_in[21];
    const float* W_out          = (const float*)d_in[22];

    const int N = in_sizes[0];
    const int E = in_sizes[2];
    const int T = in_sizes[3];
    const int* src = edge_index;
    const int* tgt = edge_index + E;

    // workspace layout, 256B-aligned. Total ~268.35 MB (ws = 256 MiB = 268.44 MB)
    char* base = (char*)d_ws;
    size_t off = 0;
    auto alloc = [&](size_t bytes) -> void* {
        void* r = base + off;
        off += (bytes + 255) & ~(size_t)255;
        return r;
    };
    bf16*  m     = (bf16*)alloc((size_t)E * DE * 2);     // 102.4 MB
    bf16*  t1    = (bf16*)alloc((size_t)E * DE * 2);     // 102.4 MB
    bf16*  rbf   = (bf16*)alloc((size_t)E * NRAD * 2);   // 25.6 MB
    bf16*  rbf3  = (bf16*)alloc((size_t)E * DCB * 2);    // 3.2 MB
    bf16*  xba   = (bf16*)alloc((size_t)E * DT * 2);     // 12.8 MB
    float* h     = (float*)alloc((size_t)N * DA * 4);    // 8.2 MB
    float* partials = (float*)alloc(4096 * 4);
    // bf16 TRANSPOSED weight copies [N][K] (~10.9 MB)
    bf16* wedgeT = (bf16*)alloc((size_t)DE * (2 * DA + NRAD) * 2);  // [512][640]
    bf16* wbaT   = (bf16*)alloc((size_t)2 * DE * DE * 2);           // [2][512][512]
    bf16* wdownT = (bf16*)alloc((size_t)2 * DT * DE * 2);           // [2][64][512]
    bf16* wtripT = (bf16*)alloc((size_t)2 * DE * DT * 2);           // [2][512][64]
    bf16* wresmT = (bf16*)alloc((size_t)8 * DE * DE * 2);           // [8][512][512]
    bf16* we2aT  = (bf16*)alloc((size_t)2 * DA * DE * 2);           // [2][256][512]
    bf16* wrbfhT = (bf16*)alloc((size_t)DE * NRAD * 2);             // [512][128]
    bf16* h_bf   = (bf16*)alloc((size_t)N * DA * 2);
    // CSR (built once; ~2.8 MB)
    int* tgt_off  = (int*)alloc((size_t)(N + 1) * 4);
    int* tgt_list = (int*)alloc((size_t)E * 4);
    int* ca_off   = (int*)alloc((size_t)(E + 1) * 4);
    int* ca_list  = (int*)alloc((size_t)T * 4);
    // aliases (disjoint liveness) inside t1 / xba:
    bf16*  x3b    = t1;                              // [E,DT] bf16, steps 8-10
    bf16*  emb16  = (bf16*)((char*)t1 + 20000000);   // [T,16] bf16, steps 7.5-8
    bf16*  wreshT = (bf16*)((char*)t1 + 40000000);   // [4][256][256] bf16, step 15 only
    int*   cur_a  = (int*)t1;                        // CSR cursors (pre-step-6 only)
    int*   cur_b  = (int*)((char*)t1 + 4000000);
    int*   bsum   = (int*)((char*)t1 + 8000000);     // scan scratch
    bf16*  s_bf   = xba;                             // [N,DE] bf16, steps 13.5-14
    bf16*  tmph_b = xba;                             // [N,DA] bf16, step 15 (xba dead)

    if (off > ws_size) {
        diag_kernel<<<1, 1, 0, stream>>>((float*)d_out, (float)(ws_size >> 20));
        return;
    }

    const dim3 blk(256);
    const dim3 blk5(512);

    // 0. weights -> bf16 transposed [N][K]
    { dim3 g(DE / 32, (2 * DA + NRAD) / 32, 1);
      t2bT_kernel<<<g, blk, 0, stream>>>(W_edge, wedgeT, 2 * DA + NRAD, DE); }
    { dim3 g(DE / 32, DE / 32, 2);
      t2bT_kernel<<<g, blk, 0, stream>>>(W_ba, wbaT, DE, DE); }
    { dim3 g(DT / 32, DE / 32, 2);
      t2bT_kernel<<<g, blk, 0, stream>>>(W_down, wdownT, DE, DT); }
    { dim3 g(DE / 32, DT / 32, 2);
      t2bT_kernel<<<g, blk, 0, stream>>>(W_trip_up, wtripT, DT, DE); }
    { dim3 g(DE / 32, DE / 32, 8);
      t2bT_kernel<<<g, blk, 0, stream>>>(W_res_m, wresmT, DE, DE); }
    { dim3 g(DA / 32, DE / 32, 2);
      t2bT_kernel<<<g, blk, 0, stream>>>(W_e2a, we2aT, DE, DA); }
    { dim3 g(DE / 32, NRAD / 32, 1);
      t2bT_kernel<<<g, blk, 0, stream>>>(W_rbf_h, wrbfhT, NRAD, DE); }

    // 0b. CSR build for tgt (E -> N segments) and ca (T -> E segments)
    {
        zeroi_kernel<<<cdiv(N, 256), blk, 0, stream>>>(cur_a, N);
        count_kernel<<<cdiv(E, 256), blk, 0, stream>>>(tgt, cur_a, E);
        seg_p1<<<cdiv(N, 256), blk, 0, stream>>>(cur_a, bsum, N);
        seg_p2<<<1, 1024, 0, stream>>>(bsum, tgt_off, cdiv(N, 256), N);
        seg_p3<<<cdiv(N, 256), blk, 0, stream>>>(cur_a, bsum, tgt_off, N);
        copyi_kernel<<<cdiv(N, 256), blk, 0, stream>>>(tgt_off, cur_a, N);
        fill_kernel<<<cdiv(E, 256), blk, 0, stream>>>(tgt, cur_a, tgt_list, E);
        zeroi_kernel<<<cdiv(E, 256), blk, 0, stream>>>(cur_b, E);
        count_kernel<<<cdiv(T, 256), blk, 0, stream>>>(id3_ca, cur_b, T);
        seg_p1<<<cdiv(E, 256), blk, 0, stream>>>(cur_b, bsum, E);
        seg_p2<<<1, 1024, 0, stream>>>(bsum, ca_off, cdiv(E, 256), E);
        seg_p3<<<cdiv(E, 256), blk, 0, stream>>>(cur_b, bsum, ca_off, E);
        copyi_kernel<<<cdiv(E, 256), blk, 0, stream>>>(ca_off, cur_b, E);
        fill_kernel<<<cdiv(T, 256), blk, 0, stream>>>(id3_ca, cur_b, ca_list, T);
    }

    // 1. basis
    basis_kernel<<<E, 128, 0, stream>>>(distances, W_rbf3, rbf, rbf3, E);
    // 2. h init + bf16 copy
    h_init_kernel<<<cdiv(N * DA, 256), blk, 0, stream>>>(atomic_numbers, atom_table, h, N);
    f2b_kernel<<<256, blk, 0, stream>>>(h, h_bf, (long)N * DA);

    // 3+4+5 fused (GMODE=3, K=640):
    // m = silu(h[src]@W_edge[0:256] + h[tgt]@W_edge[256:512] + rbf@W_edge[512:640] + b)
    {
        dim3 g(cdiv(DE, 128), cdiv(E, 128));
        gemm_mfma<bf16, bf16, 3, false, true, true, false, false>
            <<<g, blk5, 0, stream>>>(h_bf, rbf, wedgeT, m, nullptr, nullptr, b_edge,
                                     src, tgt, E, DE, 2 * DA + NRAD, DA, 2 * DA + NRAD, 1.0f);
    }

    for (int b = 0; b < 2; ++b) {
        const bf16* WbaT = wbaT + (long)b * DE * DE;
        const float* bba = b_ba + (long)b * DE;
        const bf16* WdnT = wdownT + (long)b * DT * DE;
        const bf16* WtuT = wtripT + (long)b * DE * DT;
        const bf16* We2aT = we2aT + (long)b * DA * DE;

        // 6. t1 = silu(m @ W_ba + b_ba)
        gemm_pers<bf16, bf16, false, true, true, false, false>
            <<<pers_grid(E, DE), blk5, 0, stream>>>(m, WbaT, t1, (const bf16*)nullptr,
                                                    (const bf16*)nullptr, bba,
                                                    E, DE, DE, DE, DE, 1.0f);
        // 7. xba = t1 @ W_down
        gemm_pers<bf16, bf16, false, false, false, false, false>
            <<<pers_grid(E, DT), blk5, 0, stream>>>(t1, WdnT, xba, (const bf16*)nullptr,
                                                    (const bf16*)nullptr, nullptr,
                                                    E, DT, DE, DE, DE, 1.0f);
        // 7.5 emb16 (into dead t1 space)
        emb16_kernel<<<cdiv(T * DCB, 256), blk, 0, stream>>>(cos_angles, id3_ba, rbf3,
                                                             W_sph, emb16, T);
        // 8. x3b[e] = sum over ca-bucket (no atomics)
        x3_gather_kernel<<<cdiv(E, 4), blk, 0, stream>>>(ca_off, ca_list, id3_ba,
                                                         emb16, xba, W_cbf_up, x3b, E);
        // 10. m = (m + x3b @ W_trip_up) * INV_SQRT2
        gemm_pers<bf16, bf16, true, false, false, false, false>
            <<<pers_grid(E, DE), blk5, 0, stream>>>(x3b, WtuT, m, m,
                                                    (const bf16*)nullptr, nullptr,
                                                    E, DE, DT, DT, DT, INV_SQRT2);
        // 11-12. edge residual x2
        for (int r = 0; r < 2; ++r) {
            const bf16* W0T = wresmT + (((long)b * 2 + r) * 2 + 0) * DE * DE;
            const bf16* W1T = wresmT + (((long)b * 2 + r) * 2 + 1) * DE * DE;
            const float* b0 = b_res_m + (((long)b * 2 + r) * 2 + 0) * DE;
            const float* b1 = b_res_m + (((long)b * 2 + r) * 2 + 1) * DE;
            gemm_pers<bf16, bf16, false, true, true, false, false>
                <<<pers_grid(E, DE), blk5, 0, stream>>>(m, W0T, t1, (const bf16*)nullptr,
                                                        (const bf16*)nullptr, b0,
                                                        E, DE, DE, DE, DE, 1.0f);
            gemm_pers<bf16, bf16, false, true, true, true, false>
                <<<pers_grid(E, DE), blk5, 0, stream>>>(t1, W1T, m, (const bf16*)nullptr,
                                                        m, b1,
                                                        E, DE, DE, DE, DE, INV_SQRT2);
        }
        // 13. t1 = (rbf @ W_rbf_h) * m
        gemm_pers<bf16, bf16, false, false, false, false, true>
            <<<pers_grid(E, DE), blk5, 0, stream>>>(rbf, wrbfhT, t1, (const bf16*)nullptr,
                                                    m, nullptr,
                                                    E, DE, NRAD, NRAD, NRAD, 1.0f);
        // 13.5 s_bf[a] = segment_sum(t1, tgt)   (no atomics)
        atom_segsum_kernel<<<N, blk, 0, stream>>>(tgt_off, tgt_list, t1, s_bf, N);
        // 14. h += s_bf @ W_e2a   (dense MFMA, PRE_ADD)
        gemm_pers<float, float, true, false, false, false, false>
            <<<pers_grid(N, DA), blk5, 0, stream>>>(s_bf, We2aT, h, h,
                                                    (const float*)nullptr, nullptr,
                                                    N, DA, DE, DE, DE, 1.0f);
        // 15. atom residual x2 via MFMA (weights transposed into dead t1 space).
        {
            dim3 gt(DA / 32, DA / 32, 4);
            t2bT_kernel<<<gt, blk, 0, stream>>>(W_res_h + (long)b * 4 * DA * DA,
                                                wreshT, DA, DA);
        }
        for (int r = 0; r < 2; ++r) {
            const bf16* W0T = wreshT + (long)(r * 2 + 0) * DA * DA;
            const bf16* W1T = wreshT + (long)(r * 2 + 1) * DA * DA;
            const float* b0 = b_res_h + (((long)b * 2 + r) * 2 + 0) * DA;
            const float* b1 = b_res_h + (((long)b * 2 + r) * 2 + 1) * DA;
            f2b_kernel<<<256, blk, 0, stream>>>(h, h_bf, (long)N * DA);
            gemm_pers<bf16, bf16, false, true, true, false, false>
                <<<pers_grid(N, DA), blk5, 0, stream>>>(h_bf, W0T, tmph_b,
                                                        (const bf16*)nullptr,
                                                        (const bf16*)nullptr, b0,
                                                        N, DA, DA, DA, DA, 1.0f);
            gemm_pers<float, float, false, true, true, true, false>
                <<<pers_grid(N, DA), blk5, 0, stream>>>(tmph_b, W1T, h,
                                                        (const float*)nullptr, h, b1,
                                                        N, DA, DA, DA, DA, INV_SQRT2);
        }
    }

    // 16. energy = sum(h @ W_out)
    const int nb1 = cdiv(N, 32);
    reduce1_kernel<<<nb1, blk, 0, stream>>>(h, W_out, partials, N);
    reduce2_kernel<<<1, blk, 0, stream>>>(partials, (float*)d_out, nb1);
}

// Round 21
// 2073.185 us; speedup vs baseline: 1.0416x; 1.0416x over previous
//
#include <hip/hip_runtime.h>
#include <hip/hip_bf16.h>
#include <math.h>

// ---------------- constants ----------------
#define CUTOFF 6.0f
#define NRAD 128
#define NSPH 7
#define DA 256
#define DE 512
#define DT 64
#define DCB 16
#define INV_SQRT2 0.7071067811865476f
#define RBF_GAMMA 227.55555555555554f

typedef __hip_bfloat16 bf16;
typedef __bf16 bf16v;
typedef bf16v bf16x8 __attribute__((ext_vector_type(8)));
typedef float f32x4 __attribute__((ext_vector_type(4)));

static inline int cdiv(int a, int b) { return (a + b - 1) / b; }

__device__ __forceinline__ float silu_f(float v) {
    return v / (1.0f + __expf(-v));
}

__device__ __forceinline__ float to_f(float v) { return v; }
__device__ __forceinline__ float to_f(bf16 v) { return __bfloat162float(v); }

template<typename T> __device__ __forceinline__ T from_f(float v);
template<> __device__ __forceinline__ float from_f<float>(float v) { return v; }
template<> __device__ __forceinline__ bf16 from_f<bf16>(float v) { return __float2bfloat16(v); }

#if defined(__has_builtin)
#if __has_builtin(__builtin_amdgcn_global_load_lds)
#define HAS_GLD 1
#endif
#endif

#ifdef HAS_GLD
// async 16B global->LDS: per-lane global addr, wave-uniform LDS base + lane*16
__device__ __forceinline__ void gld16(const bf16* g, bf16* l) {
    __builtin_amdgcn_global_load_lds(
        (const __attribute__((address_space(1))) void*)g,
        (__attribute__((address_space(3))) void*)l, 16, 0, 0);
}
#endif

// ================= MFMA bf16 GEMM, 128x128 tile, BK=32, 512 thr (8 waves) =========
// C[M,N] = epi( A @ Bt^T );  Bt PRE-TRANSPOSED [N][K] (ldb = row stride).
// 8 waves in 2x4 grid: wave -> 64x32 output (4x2 frags, 32 acc VGPR/lane).
// T3/T4: 3-deep LDS pipeline (3 x 16KB buffers = 48KB -> 3 blocks/CU at
// __launch_bounds__(512,6)); stages t+1,t+2 stay in flight across raw s_barrier;
// counted s_waitcnt vmcnt(4/2/0) (round-13-verified race-free pattern).
// Staging: 1 gld16/wave for A rows [16w,16w+16) and 1 for B; linear LDS [128][32],
// chunk-XOR swizzle (source permute + read permute). XCD-bijective block swizzle.
// GMODE: 0 = plain rows; 2 = dual-gather (k<DA idx1, else idx2, lda=DA);
//        3 = dual-gather + tail (k>=2*DA reads A3[row], ld=NRAD).
template<typename TC, typename TD, int GMODE, bool PRE_ADD, bool HAS_BIAS,
         bool ACT, bool POST_ADD, bool POST_MUL>
__global__ __launch_bounds__(512, 6)
void gemm_mfma(const bf16* __restrict__ A, const bf16* __restrict__ A3,
               const bf16* __restrict__ Bt,
               TC* __restrict__ C, const TC* __restrict__ Cin,
               const TD* __restrict__ Dop, const float* __restrict__ bias,
               const int* __restrict__ idx1, const int* __restrict__ idx2,
               int M, int N, int K, int lda, int ldb, float scale)
{
    __shared__ bf16 lds[3 * 8192];   // 3 bufs x (A 4096 + B 4096 elems), 48 KB
    const int tid = threadIdx.x;

    // ---- XCD-aware bijective swizzle ----
    const int nwg = gridDim.x * gridDim.y;
    const int bid = blockIdx.y * gridDim.x + blockIdx.x;
    const int q = nwg >> 3, r = nwg & 7;
    const int xcd = bid & 7, jj = bid >> 3;
    const int wg = (xcd < r) ? (xcd * (q + 1) + jj) : (r + xcd * q + jj);
    const int bn = (wg % gridDim.x) * 128;
    const int bm = (wg / gridDim.x) * 128;

    const int w   = tid >> 6;        // 0..7
    const int l   = tid & 63;
    const int l16 = l & 15;
    const int lr4 = (l >> 4) * 4;
    const int wr  = (w >> 2) * 64;   // wave row base in tile (2 wave-rows)
    const int wc  = (w & 3) * 32;    // wave col base in tile (4 wave-cols)
    // swizzled read k-offset (elems): chunk (l>>4) XOR row-hash ((l16>>1)&3)
    const int koff = (((l >> 4) ^ ((l16 >> 1) & 3)) << 3);

    f32x4 acc[4][2];
#pragma unroll
    for (int i = 0; i < 4; ++i)
#pragma unroll
        for (int j = 0; j < 2; ++j) acc[i][j] = (f32x4){0.f, 0.f, 0.f, 0.f};

    // staging map: wave w covers tile-rows [w*16, w*16+16) for BOTH A and B.
    const int csw = (((l & 3) ^ ((l >> 3) & 3)) << 3);
    const int rA = w * 16 + (l >> 2);

    int ar = bm + rA; if (ar >= M) ar = M - 1;
    const bf16* pAa = A + (long)((GMODE >= 2) ? idx1[ar] : ar) * lda + csw;
    const bf16* pAb = (GMODE >= 2) ? (A + (long)idx2[ar] * lda + csw) : pAa;
    const bf16* pAc = (GMODE == 3) ? (A3 + (long)ar * NRAD + csw) : pAa;

    int bc = bn + rA; if (bc >= N) bc = N - 1;
    const bf16* pB = Bt + (long)bc * ldb + csw;

    const int wofs = (w * 16) * 32;   // wave-uniform stage dest offset (elems)

    auto STAGE = [&](int k0, int bo) {
        const bf16* a0;
        if (GMODE == 0) {
            a0 = pAa + k0;
        } else if (GMODE == 2) {
            a0 = (k0 >= DA) ? (pAb + (k0 - DA)) : (pAa + k0);
        } else {  // GMODE == 3
            if (k0 >= 2 * DA)  a0 = pAc + (k0 - 2 * DA);
            else if (k0 >= DA) a0 = pAb + (k0 - DA);
            else               a0 = pAa + k0;
        }
#ifdef HAS_GLD
        gld16(a0, lds + bo + wofs);
        gld16(pB + k0, lds + bo + 4096 + wofs);
#else
        *(uint4*)(lds + bo + (tid >> 2) * 32 + (tid & 3) * 8) = *(const uint4*)a0;
        *(uint4*)(lds + bo + 4096 + (tid >> 2) * 32 + (tid & 3) * 8) = *(const uint4*)(pB + k0);
#endif
    };

    auto COMPUTE = [&](int bo) {
        const bf16* As_ = lds + bo;
        const bf16* Bs_ = lds + bo + 4096;
        bf16x8 bfr[2];
#pragma unroll
        for (int fn = 0; fn < 2; ++fn)
            bfr[fn] = *(const bf16x8*)&Bs_[(wc + fn * 16 + l16) * 32 + koff];
#pragma unroll
        for (int fm = 0; fm < 4; ++fm) {
            bf16x8 af = *(const bf16x8*)&As_[(wr + fm * 16 + l16) * 32 + koff];
            acc[fm][0] = __builtin_amdgcn_mfma_f32_16x16x32_bf16(af, bfr[0], acc[fm][0], 0, 0, 0);
            acc[fm][1] = __builtin_amdgcn_mfma_f32_16x16x32_bf16(af, bfr[1], acc[fm][1], 0, 0, 0);
        }
    };

    const int nt = K >> 5;

#ifdef HAS_GLD
    if (nt > 0) STAGE(0, 0);
    if (nt > 1) STAGE(32, 8192);
    int boC = 0;            // compute buffer for t
    int boS = 16384;        // stage buffer for t+2
    for (int t = 0; t < nt; ++t) {
        if (t + 2 < nt) STAGE((t + 2) << 5, boS);
        const int rem = nt - 1 - t;
        __builtin_amdgcn_sched_barrier(0);
        if (rem >= 2)      asm volatile("s_waitcnt vmcnt(4)" ::: "memory");
        else if (rem == 1) asm volatile("s_waitcnt vmcnt(2)" ::: "memory");
        else               asm volatile("s_waitcnt vmcnt(0)" ::: "memory");
        __builtin_amdgcn_sched_barrier(0);
        __builtin_amdgcn_s_barrier();
        __builtin_amdgcn_sched_barrier(0);
        COMPUTE(boC);
        __builtin_amdgcn_s_barrier();
        boC += 8192; if (boC > 16384) boC = 0;
        boS += 8192; if (boS > 16384) boS = 0;
    }
#else
    for (int t = 0; t < nt; ++t) {
        STAGE(t << 5, 0);
        __syncthreads();
        COMPUTE(0);
        __syncthreads();
    }
#endif

#pragma unroll
    for (int fm = 0; fm < 4; ++fm) {
#pragma unroll
        for (int fn = 0; fn < 2; ++fn) {
            const int col = bn + wc + fn * 16 + l16;
            if (col < N) {
#pragma unroll
                for (int r4 = 0; r4 < 4; ++r4) {
                    const int row = bm + wr + fm * 16 + lr4 + r4;
                    if (row < M) {
                        float v = acc[fm][fn][r4];
                        if (PRE_ADD)  v += to_f(Cin[(long)row * N + col]);
                        if (HAS_BIAS) v += bias[col];
                        if (ACT)      v = silu_f(v);
                        if (POST_ADD) v += to_f(Dop[(long)row * N + col]);
                        if (POST_MUL) v *= to_f(Dop[(long)row * N + col]);
                        C[(long)row * N + col] = from_f<TC>(v * scale);
                    }
                }
            }
        }
    }
}

// ---------------- f32 -> bf16 convert ----------------
__global__ void f2b_kernel(const float* __restrict__ in, bf16* __restrict__ out, long n)
{
    long i = ((long)blockIdx.x * 256 + threadIdx.x) * 4;
    const long stride = (long)gridDim.x * 256 * 4;
    for (; i < n; i += stride) {
        float4 v = *(const float4*)(in + i);
        bf16 o[4] = {__float2bfloat16(v.x), __float2bfloat16(v.y),
                     __float2bfloat16(v.z), __float2bfloat16(v.w)};
        *(ushort4*)(out + i) = *(const ushort4*)o;
    }
}

// ---------------- f32 [B][K][Nc] -> bf16 transposed [B][Nc][K] (LDS 32x32 tiles) -----
__global__ __launch_bounds__(256)
void t2bT_kernel(const float* __restrict__ in, bf16* __restrict__ out, int K, int Nc)
{
    __shared__ float tile[32][33];
    const long bofs = (long)blockIdx.z * K * Nc;
    const int k0 = blockIdx.y * 32;
    const int n0 = blockIdx.x * 32;
    const int tx = threadIdx.x & 31;
    const int ty = threadIdx.x >> 5;   // 0..7
#pragma unroll
    for (int i = 0; i < 4; ++i) {
        int k = k0 + ty + 8 * i;
        tile[ty + 8 * i][tx] = (k < K && n0 + tx < Nc) ? in[bofs + (long)k * Nc + n0 + tx] : 0.f;
    }
    __syncthreads();
#pragma unroll
    for (int i = 0; i < 4; ++i) {
        int n = n0 + ty + 8 * i;
        if (n < Nc && k0 + tx < K)
            out[bofs + (long)n * K + k0 + tx] = from_f<bf16>(tile[tx][ty + 8 * i]);
    }
}

// ---------------- radial basis ----------------
__global__ __launch_bounds__(128)
void basis_kernel(const float* __restrict__ dist,
                  const float* __restrict__ W_rbf3,
                  bf16* __restrict__ rbf, bf16* __restrict__ rbf3, int E)
{
    __shared__ float s_rbf[NRAD];
    const int e = blockIdx.x;
    if (e >= E) return;
    const int k = threadIdx.x;
    const float d = dist[e];
    const float u = d * (1.0f / CUTOFF);
    float u2 = u * u, u4 = u2 * u2, u5 = u4 * u, u6 = u5 * u, u7 = u6 * u;
    float env = 1.0f - 21.0f * u5 + 35.0f * u6 - 15.0f * u7;
    if (u >= 1.0f) env = 0.0f;
    const float mu = CUTOFF * (float)k / (float)(NRAD - 1);
    const float t = d - mu;
    const float v = env * __expf(-RBF_GAMMA * t * t);
    s_rbf[k] = v;
    rbf[(long)e * NRAD + k] = __float2bfloat16(v);
    __syncthreads();

    if (k < DCB) {
        float acc = 0.f;
        for (int kk = 0; kk < NRAD; ++kk) acc += s_rbf[kk] * W_rbf3[kk * DCB + k];
        rbf3[(long)e * DCB + k] = __float2bfloat16(acc);
    }
}

// ---------------- h init ----------------
__global__ void h_init_kernel(const int* __restrict__ an,
                              const float* __restrict__ table,
                              float* __restrict__ h, int N)
{
    int i = blockIdx.x * 256 + threadIdx.x;
    if (i < N * DA) {
        int a = i >> 8;
        int c = i & 255;
        h[i] = table[(long)an[a] * DA + c];
    }
}

// ================= CSR build =================
__global__ void zeroi_kernel(int* __restrict__ p, int n)
{
    int i = blockIdx.x * 256 + threadIdx.x;
    if (i < n) p[i] = 0;
}
__global__ void copyi_kernel(const int* __restrict__ a, int* __restrict__ b, int n)
{
    int i = blockIdx.x * 256 + threadIdx.x;
    if (i < n) b[i] = a[i];
}
__global__ void count_kernel(const int* __restrict__ idx, int* __restrict__ cnt, int n)
{
    int i = blockIdx.x * 256 + threadIdx.x;
    if (i < n) atomicAdd(&cnt[idx[i]], 1);
}
__global__ __launch_bounds__(256)
void seg_p1(const int* __restrict__ cnt, int* __restrict__ bsum, int n)
{
    __shared__ int s[256];
    int i = blockIdx.x * 256 + threadIdx.x;
    s[threadIdx.x] = (i < n) ? cnt[i] : 0;
    __syncthreads();
    for (int o = 128; o > 0; o >>= 1) {
        if (threadIdx.x < o) s[threadIdx.x] += s[threadIdx.x + o];
        __syncthreads();
    }
    if (threadIdx.x == 0) bsum[blockIdx.x] = s[0];
}
__global__ __launch_bounds__(1024)
void seg_p2(int* __restrict__ bsum, int* __restrict__ off, int nb, int n)
{
    __shared__ int s[1024];
    int v = (threadIdx.x < nb) ? bsum[threadIdx.x] : 0;
    s[threadIdx.x] = v;
    __syncthreads();
    for (int o = 1; o < 1024; o <<= 1) {
        int t = (threadIdx.x >= o) ? s[threadIdx.x - o] : 0;
        __syncthreads();
        s[threadIdx.x] += t;
        __syncthreads();
    }
    if (threadIdx.x < nb) bsum[threadIdx.x] = s[threadIdx.x] - v;  // exclusive
    if (threadIdx.x == nb - 1) off[n] = s[threadIdx.x];            // total
}
__global__ __launch_bounds__(256)
void seg_p3(const int* __restrict__ cnt, const int* __restrict__ bsum,
            int* __restrict__ off, int n)
{
    __shared__ int s[256];
    int i = blockIdx.x * 256 + threadIdx.x;
    int v = (i < n) ? cnt[i] : 0;
    s[threadIdx.x] = v;
    __syncthreads();
    for (int o = 1; o < 256; o <<= 1) {
        int t = (threadIdx.x >= o) ? s[threadIdx.x - o] : 0;
        __syncthreads();
        s[threadIdx.x] += t;
        __syncthreads();
    }
    if (i < n) off[i] = bsum[blockIdx.x] + s[threadIdx.x] - v;
}
__global__ void fill_kernel(const int* __restrict__ idx, int* __restrict__ cur,
                            int* __restrict__ list, int n)
{
    int i = blockIdx.x * 256 + threadIdx.x;
    if (i < n) {
        int p = atomicAdd(&cur[idx[i]], 1);
        list[p] = i;
    }
}

// ---------------- emb16[T,16] = (cheb(cos)@W_sph) * rbf3[ba] ----------------
__global__ __launch_bounds__(256)
void emb16_kernel(const float* __restrict__ cosang,
                  const int* __restrict__ id3_ba,
                  const bf16* __restrict__ rbf3,
                  const float* __restrict__ W_sph,
                  bf16* __restrict__ emb, int T)
{
    __shared__ float s_W[NSPH * DCB];
    const int tid = threadIdx.x;
    if (tid < NSPH * DCB) s_W[tid] = W_sph[tid];
    __syncthreads();
    const long idx = (long)blockIdx.x * 256 + tid;
    if (idx >= (long)T * DCB) return;
    const int t = (int)(idx >> 4);
    const int cc = (int)(idx & 15);
    float c = cosang[t];
    c = fminf(1.0f, fmaxf(-1.0f, c));
    float s0 = 1.0f, s1 = c;
    float a = s_W[0 * DCB + cc] + c * s_W[1 * DCB + cc];
#pragma unroll
    for (int s = 2; s < NSPH; ++s) {
        float s2 = 2.0f * c * s1 - s0;
        a += s2 * s_W[s * DCB + cc];
        s0 = s1; s1 = s2;
    }
    emb[idx] = __float2bfloat16(a * to_f(rbf3[(long)id3_ba[t] * DCB + cc]));
}

// ---------------- x3[e] = sum_{t in bucket(e)} (emb16[t] @ W_up) * xba[ba[t]] ----------------
__global__ __launch_bounds__(256)
void x3_gather_kernel(const int* __restrict__ ca_off, const int* __restrict__ ca_list,
                      const int* __restrict__ id3_ba,
                      const bf16* __restrict__ emb, const bf16* __restrict__ xba,
                      const float* __restrict__ W_up,
                      bf16* __restrict__ x3, int E)
{
    __shared__ float s_Wup[DCB * DT];
    const int tid = threadIdx.x;
    for (int i = tid; i < DCB * DT; i += 256) s_Wup[i] = W_up[i];
    __syncthreads();
    const int e = blockIdx.x * 4 + (tid >> 6);
    const int d = tid & 63;
    if (e >= E) return;
    const int j0 = ca_off[e], j1 = ca_off[e + 1];
    float acc = 0.f;
    for (int j = j0; j < j1; ++j) {
        const int t = ca_list[j];
        const int ba = id3_ba[t];
        const ushort* ep = (const ushort*)(emb + (long)t * DCB);
        float dotv = 0.f;
#pragma unroll
        for (int cc = 0; cc < DCB; ++cc)
            dotv += __uint_as_float((unsigned)ep[cc] << 16) * s_Wup[cc * DT + d];
        acc += dotv * to_f(xba[(long)ba * DT + d]);
    }
    x3[(long)e * DT + d] = from_f<bf16>(acc);
}

// ---------------- s[a] = sum_{e in bucket(a)} g[e]  (g bf16 [E,DE]) ----------------
__global__ __launch_bounds__(256)
void atom_segsum_kernel(const int* __restrict__ tgt_off, const int* __restrict__ tgt_list,
                        const bf16* __restrict__ g, bf16* __restrict__ s_out, int N)
{
    const int a = blockIdx.x;
    if (a >= N) return;
    const int c = threadIdx.x;
    float acc0 = 0.f, acc1 = 0.f;
    const int j0 = tgt_off[a], j1 = tgt_off[a + 1];
    for (int j = j0; j < j1; ++j) {
        const bf16* row = g + (long)tgt_list[j] * DE;
        acc0 += to_f(row[c]);
        acc1 += to_f(row[c + 256]);
    }
    s_out[(long)a * DE + c]       = from_f<bf16>(acc0);
    s_out[(long)a * DE + c + 256] = from_f<bf16>(acc1);
}

// ---------------- final reduce ----------------
__global__ __launch_bounds__(256)
void reduce1_kernel(const float* __restrict__ h, const float* __restrict__ Wout,
                    float* __restrict__ partials, int N)
{
    __shared__ float s[256];
    const int a0 = blockIdx.x * 32;
    const int col = threadIdx.x;
    float acc = 0.f;
    for (int a = 0; a < 32; ++a) {
        int row = a0 + a;
        if (row < N) acc += h[(long)row * DA + col];
    }
    acc *= Wout[col];
    s[col] = acc;
    __syncthreads();
    for (int off = 128; off > 0; off >>= 1) {
        if (col < off) s[col] += s[col + off];
        __syncthreads();
    }
    if (col == 0) partials[blockIdx.x] = s[0];
}

__global__ __launch_bounds__(256)
void reduce2_kernel(const float* __restrict__ partials, float* __restrict__ out, int nb)
{
    __shared__ float s[256];
    float acc = 0.f;
    for (int i = threadIdx.x; i < nb; i += 256) acc += partials[i];
    s[threadIdx.x] = acc;
    __syncthreads();
    for (int off = 128; off > 0; off >>= 1) {
        if (threadIdx.x < off) s[threadIdx.x] += s[threadIdx.x + off];
        __syncthreads();
    }
    if (threadIdx.x == 0) out[0] = s[0];
}

__global__ void diag_kernel(float* out, float v) { out[0] = v; }

// ---------------- launch ----------------
extern "C" void kernel_launch(void* const* d_in, const int* in_sizes, int n_in,
                              void* d_out, int out_size, void* d_ws, size_t ws_size,
                              hipStream_t stream)
{
    const int*   atomic_numbers = (const int*)d_in[0];
    const int*   edge_index     = (const int*)d_in[1];
    const float* distances      = (const float*)d_in[2];
    const int*   id3_ba         = (const int*)d_in[3];
    const int*   id3_ca         = (const int*)d_in[4];
    const float* cos_angles     = (const float*)d_in[5];
    const float* atom_table     = (const float*)d_in[6];
    const float* W_edge         = (const float*)d_in[7];
    const float* b_edge         = (const float*)d_in[8];
    const float* W_rbf3         = (const float*)d_in[9];
    const float* W_sph          = (const float*)d_in[10];
    const float* W_cbf_up       = (const float*)d_in[11];
    const float* W_rbf_h        = (const float*)d_in[12];
    const float* W_ba           = (const float*)d_in[13];
    const float* b_ba           = (const float*)d_in[14];
    const float* W_down         = (const float*)d_in[15];
    const float* W_trip_up      = (const float*)d_in[16];
    const float* W_res_m        = (const float*)d_in[17];
    const float* b_res_m        = (const float*)d_in[18];
    const float* W_e2a          = (const float*)d_in[19];
    const float* W_res_h        = (const float*)d_in[20];
    const float* b_res_h        = (const float*)d_in[21];
    const float* W_out          = (const float*)d_in[22];

    const int N = in_sizes[0];
    const int E = in_sizes[2];
    const int T = in_sizes[3];
    const int* src = edge_index;
    const int* tgt = edge_index + E;

    // workspace layout, 256B-aligned. Total ~268.35 MB (ws = 256 MiB = 268.44 MB)
    char* base = (char*)d_ws;
    size_t off = 0;
    auto alloc = [&](size_t bytes) -> void* {
        void* r = base + off;
        off += (bytes + 255) & ~(size_t)255;
        return r;
    };
    bf16*  m     = (bf16*)alloc((size_t)E * DE * 2);     // 102.4 MB
    bf16*  t1    = (bf16*)alloc((size_t)E * DE * 2);     // 102.4 MB
    bf16*  rbf   = (bf16*)alloc((size_t)E * NRAD * 2);   // 25.6 MB
    bf16*  rbf3  = (bf16*)alloc((size_t)E * DCB * 2);    // 3.2 MB
    bf16*  xba   = (bf16*)alloc((size_t)E * DT * 2);     // 12.8 MB
    float* h     = (float*)alloc((size_t)N * DA * 4);    // 8.2 MB
    float* partials = (float*)alloc(4096 * 4);
    // bf16 TRANSPOSED weight copies [N][K] (~10.9 MB)
    bf16* wedgeT = (bf16*)alloc((size_t)DE * (2 * DA + NRAD) * 2);  // [512][640]
    bf16* wbaT   = (bf16*)alloc((size_t)2 * DE * DE * 2);           // [2][512][512]
    bf16* wdownT = (bf16*)alloc((size_t)2 * DT * DE * 2);           // [2][64][512]
    bf16* wtripT = (bf16*)alloc((size_t)2 * DE * DT * 2);           // [2][512][64]
    bf16* wresmT = (bf16*)alloc((size_t)8 * DE * DE * 2);           // [8][512][512]
    bf16* we2aT  = (bf16*)alloc((size_t)2 * DA * DE * 2);           // [2][256][512]
    bf16* wrbfhT = (bf16*)alloc((size_t)DE * NRAD * 2);             // [512][128]
    bf16* h_bf   = (bf16*)alloc((size_t)N * DA * 2);
    // CSR (built once; ~2.8 MB)
    int* tgt_off  = (int*)alloc((size_t)(N + 1) * 4);
    int* tgt_list = (int*)alloc((size_t)E * 4);
    int* ca_off   = (int*)alloc((size_t)(E + 1) * 4);
    int* ca_list  = (int*)alloc((size_t)T * 4);
    // aliases (disjoint liveness) inside t1 / xba:
    bf16*  x3b    = t1;                              // [E,DT] bf16, steps 8-10
    bf16*  emb16  = (bf16*)((char*)t1 + 20000000);   // [T,16] bf16, steps 7.5-8
    bf16*  wreshT = (bf16*)((char*)t1 + 40000000);   // [4][256][256] bf16, step 15 only
    int*   cur_a  = (int*)t1;                        // CSR cursors (pre-step-6 only)
    int*   cur_b  = (int*)((char*)t1 + 4000000);
    int*   bsum   = (int*)((char*)t1 + 8000000);     // scan scratch
    bf16*  s_bf   = xba;                             // [N,DE] bf16, steps 13.5-14
    bf16*  tmph_b = xba;                             // [N,DA] bf16, step 15 (xba dead)

    if (off > ws_size) {
        diag_kernel<<<1, 1, 0, stream>>>((float*)d_out, (float)(ws_size >> 20));
        return;
    }

    const dim3 blk(256);
    const dim3 blk5(512);

    // 0. weights -> bf16 transposed [N][K]
    { dim3 g(DE / 32, (2 * DA + NRAD) / 32, 1);
      t2bT_kernel<<<g, blk, 0, stream>>>(W_edge, wedgeT, 2 * DA + NRAD, DE); }
    { dim3 g(DE / 32, DE / 32, 2);
      t2bT_kernel<<<g, blk, 0, stream>>>(W_ba, wbaT, DE, DE); }
    { dim3 g(DT / 32, DE / 32, 2);
      t2bT_kernel<<<g, blk, 0, stream>>>(W_down, wdownT, DE, DT); }
    { dim3 g(DE / 32, DT / 32, 2);
      t2bT_kernel<<<g, blk, 0, stream>>>(W_trip_up, wtripT, DT, DE); }
    { dim3 g(DE / 32, DE / 32, 8);
      t2bT_kernel<<<g, blk, 0, stream>>>(W_res_m, wresmT, DE, DE); }
    { dim3 g(DA / 32, DE / 32, 2);
      t2bT_kernel<<<g, blk, 0, stream>>>(W_e2a, we2aT, DE, DA); }
    { dim3 g(DE / 32, NRAD / 32, 1);
      t2bT_kernel<<<g, blk, 0, stream>>>(W_rbf_h, wrbfhT, NRAD, DE); }

    // 0b. CSR build for tgt (E -> N segments) and ca (T -> E segments)
    {
        zeroi_kernel<<<cdiv(N, 256), blk, 0, stream>>>(cur_a, N);
        count_kernel<<<cdiv(E, 256), blk, 0, stream>>>(tgt, cur_a, E);
        seg_p1<<<cdiv(N, 256), blk, 0, stream>>>(cur_a, bsum, N);
        seg_p2<<<1, 1024, 0, stream>>>(bsum, tgt_off, cdiv(N, 256), N);
        seg_p3<<<cdiv(N, 256), blk, 0, stream>>>(cur_a, bsum, tgt_off, N);
        copyi_kernel<<<cdiv(N, 256), blk, 0, stream>>>(tgt_off, cur_a, N);
        fill_kernel<<<cdiv(E, 256), blk, 0, stream>>>(tgt, cur_a, tgt_list, E);
        zeroi_kernel<<<cdiv(E, 256), blk, 0, stream>>>(cur_b, E);
        count_kernel<<<cdiv(T, 256), blk, 0, stream>>>(id3_ca, cur_b, T);
        seg_p1<<<cdiv(E, 256), blk, 0, stream>>>(cur_b, bsum, E);
        seg_p2<<<1, 1024, 0, stream>>>(bsum, ca_off, cdiv(E, 256), E);
        seg_p3<<<cdiv(E, 256), blk, 0, stream>>>(cur_b, bsum, ca_off, E);
        copyi_kernel<<<cdiv(E, 256), blk, 0, stream>>>(ca_off, cur_b, E);
        fill_kernel<<<cdiv(T, 256), blk, 0, stream>>>(id3_ca, cur_b, ca_list, T);
    }

    // 1. basis
    basis_kernel<<<E, 128, 0, stream>>>(distances, W_rbf3, rbf, rbf3, E);
    // 2. h init + bf16 copy
    h_init_kernel<<<cdiv(N * DA, 256), blk, 0, stream>>>(atomic_numbers, atom_table, h, N);
    f2b_kernel<<<256, blk, 0, stream>>>(h, h_bf, (long)N * DA);

    // 3+4+5 fused (GMODE=3, K=640):
    // m = silu(h[src]@W_edge[0:256] + h[tgt]@W_edge[256:512] + rbf@W_edge[512:640] + b)
    {
        dim3 g(cdiv(DE, 128), cdiv(E, 128));
        gemm_mfma<bf16, bf16, 3, false, true, true, false, false>
            <<<g, blk5, 0, stream>>>(h_bf, rbf, wedgeT, m, nullptr, nullptr, b_edge,
                                     src, tgt, E, DE, 2 * DA + NRAD, DA, 2 * DA + NRAD, 1.0f);
    }

    for (int b = 0; b < 2; ++b) {
        const bf16* WbaT = wbaT + (long)b * DE * DE;
        const float* bba = b_ba + (long)b * DE;
        const bf16* WdnT = wdownT + (long)b * DT * DE;
        const bf16* WtuT = wtripT + (long)b * DE * DT;
        const bf16* We2aT = we2aT + (long)b * DA * DE;

        // 6. t1 = silu(m @ W_ba + b_ba)
        {
            dim3 g(cdiv(DE, 128), cdiv(E, 128));
            gemm_mfma<bf16, bf16, 0, false, true, true, false, false>
                <<<g, blk5, 0, stream>>>(m, nullptr, WbaT, t1, nullptr, (const bf16*)nullptr,
                                         bba, nullptr, nullptr, E, DE, DE, DE, DE, 1.0f);
        }
        // 7. xba = t1 @ W_down
        {
            dim3 g(cdiv(DT, 128), cdiv(E, 128));
            gemm_mfma<bf16, bf16, 0, false, false, false, false, false>
                <<<g, blk5, 0, stream>>>(t1, nullptr, WdnT, xba, nullptr, (const bf16*)nullptr,
                                         nullptr, nullptr, nullptr, E, DT, DE, DE, DE, 1.0f);
        }
        // 7.5 emb16 (into dead t1 space)
        emb16_kernel<<<cdiv(T * DCB, 256), blk, 0, stream>>>(cos_angles, id3_ba, rbf3,
                                                             W_sph, emb16, T);
        // 8. x3b[e] = sum over ca-bucket (no atomics)
        x3_gather_kernel<<<cdiv(E, 4), blk, 0, stream>>>(ca_off, ca_list, id3_ba,
                                                         emb16, xba, W_cbf_up, x3b, E);
        // 10. m = (m + x3b @ W_trip_up) * INV_SQRT2
        {
            dim3 g(cdiv(DE, 128), cdiv(E, 128));
            gemm_mfma<bf16, bf16, 0, true, false, false, false, false>
                <<<g, blk5, 0, stream>>>(x3b, nullptr, WtuT, m, m, (const bf16*)nullptr,
                                         nullptr, nullptr, nullptr, E, DE, DT, DT, DT, INV_SQRT2);
        }
        // 11-12. edge residual x2
        for (int r = 0; r < 2; ++r) {
            const bf16* W0T = wresmT + (((long)b * 2 + r) * 2 + 0) * DE * DE;
            const bf16* W1T = wresmT + (((long)b * 2 + r) * 2 + 1) * DE * DE;
            const float* b0 = b_res_m + (((long)b * 2 + r) * 2 + 0) * DE;
            const float* b1 = b_res_m + (((long)b * 2 + r) * 2 + 1) * DE;
            dim3 g(cdiv(DE, 128), cdiv(E, 128));
            gemm_mfma<bf16, bf16, 0, false, true, true, false, false>
                <<<g, blk5, 0, stream>>>(m, nullptr, W0T, t1, nullptr, (const bf16*)nullptr,
                                         b0, nullptr, nullptr, E, DE, DE, DE, DE, 1.0f);
            gemm_mfma<bf16, bf16, 0, false, true, true, true, false>
                <<<g, blk5, 0, stream>>>(t1, nullptr, W1T, m, nullptr, m, b1,
                                         nullptr, nullptr, E, DE, DE, DE, DE, INV_SQRT2);
        }
        // 13. t1 = (rbf @ W_rbf_h) * m
        {
            dim3 g(cdiv(DE, 128), cdiv(E, 128));
            gemm_mfma<bf16, bf16, 0, false, false, false, false, true>
                <<<g, blk5, 0, stream>>>(rbf, nullptr, wrbfhT, t1, nullptr, m, nullptr,
                                         nullptr, nullptr, E, DE, NRAD, NRAD, NRAD, 1.0f);
        }
        // 13.5 s_bf[a] = segment_sum(t1, tgt)   (no atomics)
        atom_segsum_kernel<<<N, blk, 0, stream>>>(tgt_off, tgt_list, t1, s_bf, N);
        // 14. h += s_bf @ W_e2a   (dense MFMA, PRE_ADD)
        {
            dim3 g(cdiv(DA, 128), cdiv(N, 128));
            gemm_mfma<float, float, 0, true, false, false, false, false>
                <<<g, blk5, 0, stream>>>(s_bf, nullptr, We2aT, h, h, (const float*)nullptr,
                                         nullptr, nullptr, nullptr, N, DA, DE, DE, DE, 1.0f);
        }
        // 15. atom residual x2 via MFMA (weights transposed into dead t1 space).
        {
            dim3 gt(DA / 32, DA / 32, 4);
            t2bT_kernel<<<gt, blk, 0, stream>>>(W_res_h + (long)b * 4 * DA * DA,
                                                wreshT, DA, DA);
        }
        for (int r = 0; r < 2; ++r) {
            const bf16* W0T = wreshT + (long)(r * 2 + 0) * DA * DA;
            const bf16* W1T = wreshT + (long)(r * 2 + 1) * DA * DA;
            const float* b0 = b_res_h + (((long)b * 2 + r) * 2 + 0) * DA;
            const float* b1 = b_res_h + (((long)b * 2 + r) * 2 + 1) * DA;
            f2b_kernel<<<256, blk, 0, stream>>>(h, h_bf, (long)N * DA);
            dim3 g(cdiv(DA, 128), cdiv(N, 128));
            gemm_mfma<bf16, bf16, 0, false, true, true, false, false>
                <<<g, blk5, 0, stream>>>(h_bf, nullptr, W0T, tmph_b, nullptr,
                                         (const bf16*)nullptr, b0, nullptr, nullptr,
                                         N, DA, DA, DA, DA, 1.0f);
            gemm_mfma<float, float, 0, false, true, true, true, false>
                <<<g, blk5, 0, stream>>>(tmph_b, nullptr, W1T, h, nullptr, h, b1,
                                         nullptr, nullptr, N, DA, DA, DA, DA, INV_SQRT2);
        }
    }

    // 16. energy = sum(h @ W_out)
    const int nb1 = cdiv(N, 32);
    reduce1_kernel<<<nb1, blk, 0, stream>>>(h, W_out, partials, N);
    reduce2_kernel<<<1, blk, 0, stream>>>(partials, (float*)d_out, nb1);
}